// Round 3
// baseline (634.038 us; speedup 1.0000x reference)
//
#include <hip/hip_runtime.h>
#include <math.h>

#define LSEQ   8192
#define CHUNK  64
#define NCHUNK 128
#define NBATCH 2048

// ws float layout (proven ws_size >= 67.19MB in round 2: WRITE_SIZE showed v was written):
//   [0]        v (NBATCH*NCHUNK*64 = 16777216 floats)
//   [T0]       tables: P, A1, gB(tmp Bcols), K, Wh(bf16), Wl(bf16)
#define WS_V   0
#define T0     (NBATCH * NCHUNK * 64)
#define WS_P   (T0)
#define WS_A1  (T0 + 4096)
#define WS_GB  (T0 + 8192)
#define WS_K   (T0 + 12288)
#define WS_WH  (T0 + 12352)   /* 4096 floats = 8192 bf16: W hi, row-major 128x64 */
#define WS_WL  (T0 + 16448)   /* 4096 floats: W lo */

typedef float Row68[68];
typedef short bf16x8 __attribute__((ext_vector_type(8)));
typedef float f32x4  __attribute__((ext_vector_type(4)));

__device__ __forceinline__ float rl(float v, int l) {
  return __builtin_bit_cast(float,
      __builtin_amdgcn_readlane(__builtin_bit_cast(int, v), l));
}

__device__ __forceinline__ unsigned short bf16rne(float x) {
  unsigned b = __builtin_bit_cast(unsigned, x);
  return (unsigned short)((b + 0x7fffu + ((b >> 16) & 1u)) >> 16);
}
__device__ __forceinline__ void split2(float x, unsigned short& h, unsigned short& l) {
  h = bf16rne(x);
  float hf = __builtin_bit_cast(float, ((unsigned)h) << 16);
  l = bf16rne(x - hf);
}

// O = A@B (+I if addI) (+S1 if nonnull) (+S2 if nonnull). LDS 64x68 tiles.
// 256 threads, 4x4 output tile per thread, m-blocked b128 LDS reads.
// Caller must __syncthreads() before and after.
__device__ __forceinline__ void mmv2(Row68* O, Row68* Aop, Row68* Bop,
                                     Row68* S1, Row68* S2, int addI, int t) {
  const int r0 = (t >> 4) << 2;   // 0..60
  const int c0 = (t & 15) << 2;   // 0..60
  float acc[4][4];
#pragma unroll
  for (int i = 0; i < 4; ++i)
#pragma unroll
    for (int j = 0; j < 4; ++j) acc[i][j] = 0.f;

  for (int mb = 0; mb < 64; mb += 4) {
    f32x4 a[4], b[4];
#pragma unroll
    for (int i = 0; i < 4; ++i) a[i] = *(const f32x4*)&Aop[r0 + i][mb];
#pragma unroll
    for (int m = 0; m < 4; ++m) b[m] = *(const f32x4*)&Bop[mb + m][c0];
#pragma unroll
    for (int i = 0; i < 4; ++i)
#pragma unroll
      for (int m = 0; m < 4; ++m)
#pragma unroll
        for (int j = 0; j < 4; ++j)
          acc[i][j] += a[i][m] * b[m][j];
  }
#pragma unroll
  for (int i = 0; i < 4; ++i) {
#pragma unroll
    for (int j = 0; j < 4; ++j) {
      float v = acc[i][j];
      if (addI && (r0 + i) == (c0 + j)) v += 1.f;
      if (S1) v += S1[r0 + i][c0 + j];
      if (S2) v += S2[r0 + i][c0 + j];
      acc[i][j] = v;
    }
    f32x4 st = {acc[i][0], acc[i][1], acc[i][2], acc[i][3]};
    *(f32x4*)&O[r0 + i][c0] = st;
  }
}

// Precompute (single workgroup, 256 threads):
// X=hA; BL=(I+X8)(I+X4)(I+X2)(I+X) ~= (I-X)^-1 (err ~1e-16); Ab=BL(I+X);
// Bb=step*BL@B; block-doubled A1 rows / Bcols; P=Ab^64; K; W=[Kmat+D*I;Brev] bf16 hi/lo.
__global__ void __launch_bounds__(256)
ssm_pre(const float* __restrict__ Ag, const float* __restrict__ Bg,
        const float* __restrict__ Cg, const float* __restrict__ Dg,
        const float* __restrict__ lsg, float* __restrict__ ws) {
  __shared__ float s0[64][68], s1[64][68], s2[64][68], s3[64][68], s4[64][68];
  __shared__ float Bb0[64];
  Row68 *b0 = s0, *b1 = s1, *b2 = s2, *b3 = s3, *b4 = s4;
  const int t = threadIdx.x;
  const float step = expf(lsg[0]);
  const float h = 0.5f * step;
  const float D0 = Dg[0];

  float* wsP  = ws + WS_P;
  float* wsA1 = ws + WS_A1;
  float* gB   = ws + WS_GB;
  float* wsK  = ws + WS_K;

  // X = h*A
  for (int i = t; i < 4096; i += 256) {
    int r = i >> 6, c = i & 63;
    b0[r][c] = h * Ag[i];
  }
  __syncthreads();

  mmv2(b1, b0, b0, nullptr, nullptr, 0, t);  __syncthreads();   // X2
  mmv2(b2, b1, b1, nullptr, nullptr, 0, t);  __syncthreads();   // X4
  mmv2(b3, b2, b2, nullptr, nullptr, 0, t);  __syncthreads();   // X8
  // T1 = (I+X8)(I+X4) = X8@X4 + X8 + X4 + I
  mmv2(b4, b3, b2, b3, b2, 1, t);            __syncthreads();   // T1 -> b4
  // T2 = T1@X2 + T1
  mmv2(b2, b4, b1, b4, nullptr, 0, t);       __syncthreads();   // T2 -> b2 (X4 dead)
  // BL = T2@X + T2
  mmv2(b3, b2, b0, b2, nullptr, 0, t);       __syncthreads();   // BL -> b3 (X8 dead)
  // Ab = BL@X + BL
  mmv2(b4, b3, b0, b3, nullptr, 0, t);       __syncthreads();   // Ab -> b4 (T1 dead)

  // Bb = step * BL @ B ; A1[0] = C @ Ab ; gB[0] = Bb
  if (t < 64) {
    float acc = 0.f;
    for (int m = 0; m < 64; ++m) acc += b3[t][m] * Bg[m];
    Bb0[t] = step * acc;
    float a1 = 0.f;
    for (int m = 0; m < 64; ++m) a1 += Cg[m] * b4[m][t];
    wsA1[t] = a1;
  }
  __syncthreads();
  if (t < 64) gB[t] = Bb0[t];
  __syncthreads();

  // Block-doubling. pw = Ab^k. Free pool for squarings: b0,b1,b2,b3.
  Row68* pw = b4;
  Row68* fr[4] = {b0, b1, b2, b3};
  int fi = 0;
  for (int k = 1; k <= 32; k <<= 1) {
    for (int i = t; i < k * 64; i += 256) {
      int j = i >> 6, n = i & 63;
      float acc = 0.f;
      for (int m = 0; m < 64; ++m) acc += pw[n][m] * gB[j * 64 + m];
      gB[(k + j) * 64 + n] = acc;
    }
    for (int i = t; i < k * 64; i += 256) {
      int j = i >> 6, n = i & 63;
      float acc = 0.f;
      for (int m = 0; m < 64; ++m) acc += wsA1[j * 64 + m] * pw[m][n];
      wsA1[(k + j) * 64 + n] = acc;
    }
    __syncthreads();
    if (k < 32) {
      Row68* tgt = fr[fi]; fi = (fi + 1) & 3;
      mmv2(tgt, pw, pw, nullptr, nullptr, 0, t);
      __syncthreads();
      pw = tgt;
    }
  }
  // P = Ab^64
  {
    Row68* tgt = fr[fi];
    mmv2(tgt, pw, pw, nullptr, nullptr, 0, t);
    __syncthreads();
    for (int i = t; i < 4096; i += 256) wsP[i] = tgt[i >> 6][i & 63];
  }
  // K[r] = C . Bcols[r]
  if (t < 64) {
    float acc = 0.f;
    for (int m = 0; m < 64; ++m) acc += Cg[m] * gB[t * 64 + m];
    wsK[t] = acc;
  }
  __syncthreads();
  // W (128x64): rows 0..63 = Kmat + D*I ; rows 64..127 = Brev[n][j]=Bcols[63-j][n]
  unsigned short* wh = (unsigned short*)(ws + WS_WH);
  unsigned short* wl = (unsigned short*)(ws + WS_WL);
  for (int e = t; e < 8192; e += 256) {
    int i = e >> 6, j = e & 63;
    float w;
    if (i < 64) w = ((i >= j) ? wsK[i - j] : 0.f) + ((i == j) ? D0 : 0.f);
    else        w = gB[(63 - j) * 64 + (i - 64)];
    unsigned short hh, ll;
    split2(w, hh, ll);
    wh[e] = hh;
    wl[e] = ll;
  }
}

// Phase 1: [y0; v] = W @ U via MFMA bf16x2 (hi*hi + hi*lo + lo*hi, fp32 acc).
// Wave tile: 16 chunk-columns x 128 rows (8 row-tiles), K=64 (2 ksteps).
// 4 column-groups per wave; 4096 waves total.
__global__ void __launch_bounds__(256, 2)
ssm_conv_mfma(const float* __restrict__ u, const float* __restrict__ ws,
              float* __restrict__ y, float* __restrict__ v) {
  const int lane = threadIdx.x & 63;
  const int n = lane & 15, quad = lane >> 4;
  const int wid = blockIdx.x * 4 + (threadIdx.x >> 6);

  const unsigned short* wh = (const unsigned short*)(ws + WS_WH);
  const unsigned short* wl = (const unsigned short*)(ws + WS_WL);

  // A-fragments: A[m=lane&15][k=quad*8+j] ; row-tile t covers rows t*16+m.
  bf16x8 ah[8][2], al[8][2];
#pragma unroll
  for (int t = 0; t < 8; ++t)
#pragma unroll
    for (int ks = 0; ks < 2; ++ks) {
      int off = (t * 16 + n) * 64 + ks * 32 + quad * 8;
      ah[t][ks] = *(const bf16x8*)(wh + off);
      al[t][ks] = *(const bf16x8*)(wl + off);
    }

#pragma unroll
  for (int g = 0; g < 4; ++g) {
    const int G = wid * 4 + g;          // 0..16383
    const int row = G >> 3;             // batch row
    const int c = ((G & 7) << 4) + n;   // chunk index 0..127 (this lane's column)
    const float* ub = u + (size_t)row * LSEQ + c * 64 + quad * 8;
    f32x4 f0 = *(const f32x4*)(ub);
    f32x4 f1 = *(const f32x4*)(ub + 4);
    f32x4 f2 = *(const f32x4*)(ub + 32);
    f32x4 f3 = *(const f32x4*)(ub + 36);

    bf16x8 bh0, bl0, bh1, bl1;
    {
      float xs0[8] = {f0[0], f0[1], f0[2], f0[3], f1[0], f1[1], f1[2], f1[3]};
      float xs1[8] = {f2[0], f2[1], f2[2], f2[3], f3[0], f3[1], f3[2], f3[3]};
#pragma unroll
      for (int j = 0; j < 8; ++j) {
        unsigned short hh, ll;
        split2(xs0[j], hh, ll);
        bh0[j] = (short)hh; bl0[j] = (short)ll;
        split2(xs1[j], hh, ll);
        bh1[j] = (short)hh; bl1[j] = (short)ll;
      }
    }

    float* ybase = y + (size_t)row * LSEQ + c * 64;
    float* vbase = v + ((size_t)row * NCHUNK + c) * 64;
#pragma unroll
    for (int t = 0; t < 8; ++t) {
      f32x4 acc = {0.f, 0.f, 0.f, 0.f};
      acc = __builtin_amdgcn_mfma_f32_16x16x32_bf16(ah[t][0], bh0, acc, 0, 0, 0);
      acc = __builtin_amdgcn_mfma_f32_16x16x32_bf16(ah[t][1], bh1, acc, 0, 0, 0);
      acc = __builtin_amdgcn_mfma_f32_16x16x32_bf16(ah[t][0], bl0, acc, 0, 0, 0);
      acc = __builtin_amdgcn_mfma_f32_16x16x32_bf16(ah[t][1], bl1, acc, 0, 0, 0);
      acc = __builtin_amdgcn_mfma_f32_16x16x32_bf16(al[t][0], bh0, acc, 0, 0, 0);
      acc = __builtin_amdgcn_mfma_f32_16x16x32_bf16(al[t][1], bh1, acc, 0, 0, 0);
      const int i0 = t * 16 + quad * 4;   // C/D: col=lane&15, row=quad*4+reg
      if (t < 4) *(f32x4*)(ybase + i0) = acc;
      else       *(f32x4*)(vbase + (i0 - 64)) = acc;
    }
  }
}

// Phase 2: per-row scan. s <- P s + v_c ; y[c] += A1 s_old. ILP-4 chains.
__global__ void __launch_bounds__(256)
ssm_scan(const float* __restrict__ ws, const float* __restrict__ v,
         float* __restrict__ y) {
  const int lane = threadIdx.x & 63;
  const int row  = (blockIdx.x << 2) + (threadIdx.x >> 6);

  const float* wsP  = ws + WS_P;
  const float* wsA1 = ws + WS_A1;

  float pr[64], ar[64];
#pragma unroll
  for (int q = 0; q < 16; ++q) {
    f32x4 a = *(const f32x4*)(wsP + lane * 64 + 4 * q);
    pr[4*q] = a[0]; pr[4*q+1] = a[1]; pr[4*q+2] = a[2]; pr[4*q+3] = a[3];
    f32x4 b = *(const f32x4*)(wsA1 + lane * 64 + 4 * q);
    ar[4*q] = b[0]; ar[4*q+1] = b[1]; ar[4*q+2] = b[2]; ar[4*q+3] = b[3];
  }

  const float* vrow = v + (size_t)row * NCHUNK * 64;
  float*       yrow = y + (size_t)row * LSEQ;

  float s = 0.f;
  float pv = vrow[lane];
  float py = yrow[lane];

  for (int c = 0; c < NCHUNK; ++c) {
    float xcur = pv, ycur = py;
    if (c + 1 < NCHUNK) {
      pv = vrow[(c + 1) * 64 + lane];
      py = yrow[(c + 1) * 64 + lane];
    }
    float sa[4] = {xcur, 0.f, 0.f, 0.f};
    float ya[4] = {ycur, 0.f, 0.f, 0.f};
#pragma unroll
    for (int mb = 0; mb < 16; ++mb) {
#pragma unroll
      for (int i = 0; i < 4; ++i) {
        int m = mb * 4 + i;
        float sm = rl(s, m);
        ya[i] += ar[m] * sm;
        sa[i] += pr[m] * sm;
      }
    }
    s = (sa[0] + sa[1]) + (sa[2] + sa[3]);
    yrow[c * CHUNK + lane] = (ya[0] + ya[1]) + (ya[2] + ya[3]);
  }
}

extern "C" void kernel_launch(void* const* d_in, const int* in_sizes, int n_in,
                              void* d_out, int out_size, void* d_ws, size_t ws_size,
                              hipStream_t stream) {
  const float* u  = (const float*)d_in[0];
  const float* A  = (const float*)d_in[1];
  const float* B  = (const float*)d_in[2];
  const float* C  = (const float*)d_in[3];
  const float* D  = (const float*)d_in[4];
  const float* ls = (const float*)d_in[5];
  float* ws  = (float*)d_ws;
  float* out = (float*)d_out;
  float* v   = ws + WS_V;

  ssm_pre<<<dim3(1), dim3(256), 0, stream>>>(A, B, C, D, ls, ws);
  ssm_conv_mfma<<<dim3(1024), dim3(256), 0, stream>>>(u, ws, out, v);
  ssm_scan<<<dim3(NBATCH / 4), dim3(256), 0, stream>>>(ws, v, out);
}

// Round 4
// 406.095 us; speedup vs baseline: 1.5613x; 1.5613x over previous
//
#include <hip/hip_runtime.h>
#include <math.h>

#define LSEQ   8192
#define CHUNK  64
#define NCHUNK 128
#define NBATCH 2048

// ws float layout:
//   [0]        v (NBATCH*NCHUNK*64 = 16777216 floats)
//   [T0]       tables: P, A1, K, Wh(bf16), Wl(bf16)
#define WS_V   0
#define T0     (NBATCH * NCHUNK * 64)
#define WS_P   (T0)
#define WS_A1  (T0 + 4096)
#define WS_K   (T0 + 8192)
#define WS_WH  (T0 + 8256)    /* 4096 floats = 8192 bf16: W hi, row-major 128x64 */
#define WS_WL  (T0 + 12352)   /* 4096 floats: W lo */

typedef short bf16x8 __attribute__((ext_vector_type(8)));
typedef float f32x4  __attribute__((ext_vector_type(4)));

__device__ __forceinline__ float rl(float v, int l) {
  return __builtin_bit_cast(float,
      __builtin_amdgcn_readlane(__builtin_bit_cast(int, v), l));
}

__device__ __forceinline__ unsigned short bf16rne(float x) {
  unsigned b = __builtin_bit_cast(unsigned, x);
  return (unsigned short)((b + 0x7fffu + ((b >> 16) & 1u)) >> 16);
}
__device__ __forceinline__ void split2(float x, unsigned short& h, unsigned short& l) {
  h = bf16rne(x);
  float hf = __builtin_bit_cast(float, ((unsigned)h) << 16);
  l = bf16rne(x - hf);
}

// ---------------- pre: readlane-based 64x64 matmul, 256 thr = 4 waves ----------
// O[i][c] = sum_m A[i][m-?]... general form:
//   O[i][c] (+= I/S1/S2) = sum_m A[i - aShift][m] * B[m][c - bShift]
// stored only for i in [rLo,rHi), c in [cLo,cHi). Row-major stride 64 LDS.
// Lane = c; wave w owns rows 16w..16w+15; A-elements broadcast via v_readlane.
// All LDS accesses are stride-1 across lanes (2 lanes/bank = free).
__device__ __forceinline__ void mm_rl(
    float* __restrict__ dst, const float* __restrict__ Abuf,
    const float* __restrict__ Bbuf, const float* __restrict__ S1,
    const float* __restrict__ S2, int addI,
    int aShift, int bShift, int rLo, int rHi, int cLo, int cHi) {
  __syncthreads();   // prior mm's stores visible; prior reads complete
  const int lane = threadIdx.x & 63;
  const int rb   = (threadIdx.x >> 6) << 4;
  int bi = lane - bShift;
  bi = bi < 0 ? 0 : (bi > 63 ? 63 : bi);

  float a[16];
#pragma unroll
  for (int j = 0; j < 16; ++j) {
    int r = rb + j - aShift;
    r = r < 0 ? 0 : (r > 63 ? 63 : r);
    a[j] = Abuf[r * 64 + lane];     // lane m of this wave holds A[r][m]
  }
  float o[16];
#pragma unroll
  for (int j = 0; j < 16; ++j) o[j] = 0.f;

#pragma unroll 4
  for (int m = 0; m < 64; ++m) {
    float bv = Bbuf[m * 64 + bi];
#pragma unroll
    for (int j = 0; j < 16; ++j)
      o[j] += rl(a[j], m) * bv;     // readlane: uniform SGPR lane index
  }

#pragma unroll
  for (int j = 0; j < 16; ++j) {
    const int i = rb + j;
    float v = o[j];
    if (addI && i == lane) v += 1.f;
    if (S1) v += S1[i * 64 + lane];
    if (S2) v += S2[i * 64 + lane];
    if (i >= rLo && i < rHi && lane >= cLo && lane < cHi)
      dst[i * 64 + lane] = v;
  }
}

// Precompute (single workgroup, 256 threads):
// X=hA; BL=(I+X4)(I+X2)(I+X) ~= (I-X)^-1 (err ~1e-8); Ab=BL(I+X); Bb=step*BL@B;
// block-doubled A1 rows / gB cols; P=Ab^64; K; W=[Kmat+D*I;Brev] bf16 hi/lo.
__global__ void __launch_bounds__(256)
ssm_pre(const float* __restrict__ Ag, const float* __restrict__ Bg,
        const float* __restrict__ Cg, const float* __restrict__ Dg,
        const float* __restrict__ lsg, float* __restrict__ ws) {
  __shared__ float LDS[7 * 4096 + 64];
  float* L0  = LDS;
  float* L1  = LDS + 4096;
  float* L2  = LDS + 2 * 4096;
  float* L3  = LDS + 3 * 4096;
  float* L4  = LDS + 4 * 4096;
  float* gBl = LDS + 5 * 4096;   // gB[m][j] = (Ab^j Bb)[m], row-major
  float* A1l = LDS + 6 * 4096;   // A1 row i = C*Ab^(i+1)
  float* Kl  = LDS + 7 * 4096;

  const int t = threadIdx.x;
  const float step = expf(lsg[0]);
  const float h = 0.5f * step;
  const float D0 = Dg[0];

  // X = h*A
  for (int i = t; i < 4096; i += 256) L0[i] = h * Ag[i];

  mm_rl(L1, L0, L0, nullptr, nullptr, 0, 0, 0, 0, 64, 0, 64);   // X2
  mm_rl(L2, L1, L1, nullptr, nullptr, 0, 0, 0, 0, 64, 0, 64);   // X4
  mm_rl(L3, L2, L1, L2, L1, 1, 0, 0, 0, 64, 0, 64);             // T1=(I+X4)(I+X2)
  mm_rl(L4, L3, L0, L3, nullptr, 0, 0, 0, 0, 64, 0, 64);        // BL=T1(I+X)
  mm_rl(L2, L4, L0, L4, nullptr, 0, 0, 0, 0, 64, 0, 64);        // Ab=BL(I+X) -> L2
  __syncthreads();

  // Bb -> gB col 0 ; A1 row 0 = C@Ab
  if (t < 64) {
    float acc = 0.f, a1 = 0.f;
    for (int m = 0; m < 64; ++m) acc += L4[t * 64 + m] * Bg[m];
    gBl[t * 64] = step * acc;
    for (int m = 0; m < 64; ++m) a1 += Cg[m] * L2[m * 64 + t];
    A1l[t] = a1;
  }

  // Block-doubling: pw = Ab^k. Ext cols/rows [k,2k), then square.
  float* pw = L2;
  float* freebuf[4] = {L0, L1, L3, L4};
  int fi = 0;
  for (int k = 1; k <= 32; k <<= 1) {
    mm_rl(gBl, pw, gBl, nullptr, nullptr, 0, 0, k, 0, 64, k, 2 * k);
    mm_rl(A1l, A1l, pw, nullptr, nullptr, 0, k, 0, k, 2 * k, 0, 64);
    if (k < 32) {
      float* d = freebuf[fi]; fi = (fi + 1) & 3;
      mm_rl(d, pw, pw, nullptr, nullptr, 0, 0, 0, 0, 64, 0, 64);
      pw = d;
    }
  }
  // P = Ab^64 -> L2 (Ab long dead)
  mm_rl(L2, pw, pw, nullptr, nullptr, 0, 0, 0, 0, 64, 0, 64);
  __syncthreads();

  // K[r] = C . gB col r
  if (t < 64) {
    float acc = 0.f;
    for (int m = 0; m < 64; ++m) acc += Cg[m] * gBl[m * 64 + t];
    Kl[t] = acc;
  }
  __syncthreads();

  // Outputs
  float* wsP  = ws + WS_P;
  float* wsA1 = ws + WS_A1;
  for (int e = t; e < 4096; e += 256) {
    wsP[e]  = L2[e];
    wsA1[e] = A1l[e];
  }
  unsigned short* wh = (unsigned short*)(ws + WS_WH);
  unsigned short* wl = (unsigned short*)(ws + WS_WL);
  for (int e = t; e < 8192; e += 256) {
    int i = e >> 6, j = e & 63;
    float w;
    if (i < 64) w = ((i >= j) ? Kl[i - j] : 0.f) + ((i == j) ? D0 : 0.f);
    else        w = gBl[(i - 64) * 64 + (63 - j)];   // Brev[n][j]=(Ab^(63-j)Bb)[n]
    unsigned short hh, ll;
    split2(w, hh, ll);
    wh[e] = hh;
    wl[e] = ll;
  }
}

// Phase 1: [y0; v] = W @ U via MFMA bf16x2 (hi*hi + hi*lo + lo*hi, fp32 acc).
__global__ void __launch_bounds__(256, 2)
ssm_conv_mfma(const float* __restrict__ u, const float* __restrict__ ws,
              float* __restrict__ y, float* __restrict__ v) {
  const int lane = threadIdx.x & 63;
  const int n = lane & 15, quad = lane >> 4;
  const int wid = blockIdx.x * 4 + (threadIdx.x >> 6);

  const unsigned short* wh = (const unsigned short*)(ws + WS_WH);
  const unsigned short* wl = (const unsigned short*)(ws + WS_WL);

  bf16x8 ah[8][2], al[8][2];
#pragma unroll
  for (int t = 0; t < 8; ++t)
#pragma unroll
    for (int ks = 0; ks < 2; ++ks) {
      int off = (t * 16 + n) * 64 + ks * 32 + quad * 8;
      ah[t][ks] = *(const bf16x8*)(wh + off);
      al[t][ks] = *(const bf16x8*)(wl + off);
    }

#pragma unroll
  for (int g = 0; g < 4; ++g) {
    const int G = wid * 4 + g;
    const int row = G >> 3;
    const int c = ((G & 7) << 4) + n;
    const float* ub = u + (size_t)row * LSEQ + c * 64 + quad * 8;
    f32x4 f0 = *(const f32x4*)(ub);
    f32x4 f1 = *(const f32x4*)(ub + 4);
    f32x4 f2 = *(const f32x4*)(ub + 32);
    f32x4 f3 = *(const f32x4*)(ub + 36);

    bf16x8 bh0, bl0, bh1, bl1;
    {
      float xs0[8] = {f0[0], f0[1], f0[2], f0[3], f1[0], f1[1], f1[2], f1[3]};
      float xs1[8] = {f2[0], f2[1], f2[2], f2[3], f3[0], f3[1], f3[2], f3[3]};
#pragma unroll
      for (int j = 0; j < 8; ++j) {
        unsigned short hh, ll;
        split2(xs0[j], hh, ll);
        bh0[j] = (short)hh; bl0[j] = (short)ll;
        split2(xs1[j], hh, ll);
        bh1[j] = (short)hh; bl1[j] = (short)ll;
      }
    }

    float* ybase = y + (size_t)row * LSEQ + c * 64;
    float* vbase = v + ((size_t)row * NCHUNK + c) * 64;
#pragma unroll
    for (int t = 0; t < 8; ++t) {
      f32x4 acc = {0.f, 0.f, 0.f, 0.f};
      acc = __builtin_amdgcn_mfma_f32_16x16x32_bf16(ah[t][0], bh0, acc, 0, 0, 0);
      acc = __builtin_amdgcn_mfma_f32_16x16x32_bf16(ah[t][1], bh1, acc, 0, 0, 0);
      acc = __builtin_amdgcn_mfma_f32_16x16x32_bf16(ah[t][0], bl0, acc, 0, 0, 0);
      acc = __builtin_amdgcn_mfma_f32_16x16x32_bf16(ah[t][1], bl1, acc, 0, 0, 0);
      acc = __builtin_amdgcn_mfma_f32_16x16x32_bf16(al[t][0], bh0, acc, 0, 0, 0);
      acc = __builtin_amdgcn_mfma_f32_16x16x32_bf16(al[t][1], bh1, acc, 0, 0, 0);
      const int i0 = t * 16 + quad * 4;
      if (t < 4) *(f32x4*)(ybase + i0) = acc;
      else       *(f32x4*)(vbase + (i0 - 64)) = acc;
    }
  }
}

// Phase 2: per-row scan. s <- P s + v_c ; y[c] += A1 s_old. ILP-4 chains.
__global__ void __launch_bounds__(256)
ssm_scan(const float* __restrict__ ws, const float* __restrict__ v,
         float* __restrict__ y) {
  const int lane = threadIdx.x & 63;
  const int row  = (blockIdx.x << 2) + (threadIdx.x >> 6);

  const float* wsP  = ws + WS_P;
  const float* wsA1 = ws + WS_A1;

  float pr[64], ar[64];
#pragma unroll
  for (int q = 0; q < 16; ++q) {
    f32x4 a = *(const f32x4*)(wsP + lane * 64 + 4 * q);
    pr[4*q] = a[0]; pr[4*q+1] = a[1]; pr[4*q+2] = a[2]; pr[4*q+3] = a[3];
    f32x4 b = *(const f32x4*)(wsA1 + lane * 64 + 4 * q);
    ar[4*q] = b[0]; ar[4*q+1] = b[1]; ar[4*q+2] = b[2]; ar[4*q+3] = b[3];
  }

  const float* vrow = v + (size_t)row * NCHUNK * 64;
  float*       yrow = y + (size_t)row * LSEQ;

  float s = 0.f;
  float pv = vrow[lane];
  float py = yrow[lane];

  for (int c = 0; c < NCHUNK; ++c) {
    float xcur = pv, ycur = py;
    if (c + 1 < NCHUNK) {
      pv = vrow[(c + 1) * 64 + lane];
      py = yrow[(c + 1) * 64 + lane];
    }
    float sa[4] = {xcur, 0.f, 0.f, 0.f};
    float ya[4] = {ycur, 0.f, 0.f, 0.f};
#pragma unroll
    for (int mb = 0; mb < 16; ++mb) {
#pragma unroll
      for (int i = 0; i < 4; ++i) {
        int m = mb * 4 + i;
        float sm = rl(s, m);
        ya[i] += ar[m] * sm;
        sa[i] += pr[m] * sm;
      }
    }
    s = (sa[0] + sa[1]) + (sa[2] + sa[3]);
    yrow[c * CHUNK + lane] = (ya[0] + ya[1]) + (ya[2] + ya[3]);
  }
}

extern "C" void kernel_launch(void* const* d_in, const int* in_sizes, int n_in,
                              void* d_out, int out_size, void* d_ws, size_t ws_size,
                              hipStream_t stream) {
  const float* u  = (const float*)d_in[0];
  const float* A  = (const float*)d_in[1];
  const float* B  = (const float*)d_in[2];
  const float* C  = (const float*)d_in[3];
  const float* D  = (const float*)d_in[4];
  const float* ls = (const float*)d_in[5];
  float* ws  = (float*)d_ws;
  float* out = (float*)d_out;
  float* v   = ws + WS_V;

  ssm_pre<<<dim3(1), dim3(256), 0, stream>>>(A, B, C, D, ls, ws);
  ssm_conv_mfma<<<dim3(1024), dim3(256), 0, stream>>>(u, ws, out, v);
  ssm_scan<<<dim3(NBATCH / 4), dim3(256), 0, stream>>>(ws, v, out);
}